// Round 7
// baseline (167.475 us; speedup 1.0000x reference)
//
#include <hip/hip_runtime.h>

#define D 256     // D_IN == D_OUT == 256
#define CAP 64    // ELL row capacity (deg ~ Poisson(16); P(>64) ~ 0)
#define CHUNK 4096
#define BMT 128
#define BNT 128
#define BK 32
#define PK 40

typedef __attribute__((ext_vector_type(4))) float f32x4;
typedef __attribute__((ext_vector_type(8))) short s16x8;
typedef __attribute__((ext_vector_type(4))) unsigned short u16x4;

static __device__ __forceinline__ unsigned short f2bf(float f) {
    unsigned int u = __float_as_uint(f);
    unsigned int r = (u + 0x7fffu + ((u >> 16) & 1u)) >> 16;  // RTNE
    return (unsigned short)r;
}

// HW_REG_XCC_ID (id=20, offset 0, width 32). If the id is wrong we just lose
// locality, never correctness (claim cascade below covers all work).
static __device__ __forceinline__ int xcc_id() {
    return (int)(__builtin_amdgcn_s_getreg(((32 - 1) << 11) | 20) & 7u);
}

// ---------------- Stage A: transpose_w (blocks 0..255) ∥ hist (blocks 256..) ----------------
__global__ __launch_bounds__(256) void k_prep(const float* __restrict__ W,
                                              unsigned short* __restrict__ Wt,
                                              const int* __restrict__ dst,
                                              int* __restrict__ partial,
                                              int* __restrict__ rowSum,
                                              int E, int nch, int nb) {
    __shared__ float s[16][17];
    __shared__ int lh[256];
    const int t = threadIdx.x;
    if ((int)blockIdx.x < 256) {
        const int lk = t & 15, ln = t >> 4;
        const int k0 = ((int)blockIdx.x & 15) * 16;
        const int n0 = ((int)blockIdx.x >> 4) * 16;
        s[ln][lk] = W[(k0 + ln) * D + n0 + lk];
        __syncthreads();
        Wt[(n0 + ln) * D + k0 + lk] = f2bf(s[lk][ln]);
        return;
    }
    const int c = (int)blockIdx.x - 256;
    lh[t] = 0;
    __syncthreads();
    const int base = c * CHUNK;
    for (int k = 0; k < CHUNK; k += 256) {
        const int e = base + k + t;
        if (e < E) atomicAdd(&lh[dst[e] >> 8], 1);
    }
    __syncthreads();
    if (t < nb) {
        partial[t * nch + c] = lh[t];
        if (lh[t]) atomicAdd(&rowSum[t], lh[t]);
    }
}

// ---------------- Stage B: rowscan (blocks < nscan) ∥ bstart (last block) ----------------
__global__ __launch_bounds__(256) void k_scan(int* __restrict__ partial,
                                              const int* __restrict__ rowSum,
                                              int* __restrict__ bucketStart,
                                              int nch, int nb, int nscan) {
    if ((int)blockIdx.x < nscan) {
        const int bkt = blockIdx.x * 4 + (threadIdx.x >> 6);
        if (bkt >= nb) return;
        const int lane = threadIdx.x & 63;
        int running = 0;
        for (int k = 0; k < nch; k += 64) {
            const int idx = k + lane;
            int v = (idx < nch) ? partial[bkt * nch + idx] : 0;
            int incl = v;
            #pragma unroll
            for (int sft = 1; sft < 64; sft <<= 1) {
                const int u = __shfl_up(incl, sft, 64);
                if (lane >= sft) incl += u;
            }
            if (idx < nch) partial[bkt * nch + idx] = running + incl - v;
            running += __shfl(incl, 63, 64);
        }
        return;
    }
    __shared__ int wsum[4];
    const int t = threadIdx.x;
    const int lane = t & 63;
    const int w = t >> 6;
    const int v = (t < nb) ? rowSum[t] : 0;
    int incl = v;
    #pragma unroll
    for (int sft = 1; sft < 64; sft <<= 1) {
        const int u = __shfl_up(incl, sft, 64);
        if (lane >= sft) incl += u;
    }
    if (lane == 63) wsum[w] = incl;
    __syncthreads();
    if (t == 0) {
        int acc = 0;
        for (int i = 0; i < 4; ++i) { const int u = wsum[i]; wsum[i] = acc; acc += u; }
    }
    __syncthreads();
    const int ex = incl - v + wsum[w];
    if (t <= nb) bucketStart[t] = ex;
}

// ---------------- Stage C: scatter (blocks < nch) ∥ GEMM (rest) ----------------
__global__ __launch_bounds__(256) void k_main(
    const int* __restrict__ src, const int* __restrict__ dstp,
    const float* __restrict__ val, const int* __restrict__ partial,
    const int* __restrict__ bucketStart, int2* __restrict__ eds,
    int E, int nch, int nb,
    const float* __restrict__ x, const unsigned short* __restrict__ Wt,
    unsigned short* __restrict__ h, int M) {

    __shared__ unsigned short ws[BNT][PK];
    __shared__ unsigned short xs[BMT][PK];
    __shared__ int cur[256];
    const int t = threadIdx.x;

    if ((int)blockIdx.x < nch) {
        const int c = blockIdx.x;
        if (t < nb) cur[t] = bucketStart[t] + partial[t * nch + c];
        __syncthreads();
        const int base = c * CHUNK;
        for (int k = 0; k < CHUNK; k += 256) {
            const int e = base + k + t;
            if (e < E) {
                const int d = dstp[e];
                const int sv = src[e];
                const float v = val[e];
                const int pos = atomicAdd(&cur[d >> 8], 1);
                eds[pos] = make_int2(sv | ((d & 255) << 24), __float_as_int(v));
            }
        }
        return;
    }

    // ---- GEMM ----
    const int gb = (int)blockIdx.x - nch;
    const int bm = (gb >> 1) * BMT;
    const int bn = (gb & 1) * BNT;
    const int lane = t & 63;
    const int wid  = t >> 6;
    const int wm   = wid & 1;
    const int wn   = wid >> 1;
    const int l15  = lane & 15;
    const int l4   = lane >> 4;
    const int srow = t >> 3;
    const int q    = t & 7;

    f32x4 acc[4][4] = {};

    for (int k0 = 0; k0 < D; k0 += BK) {
        #pragma unroll
        for (int p = 0; p < 4; ++p) {
            const int row = srow + p * 32;
            float4 v = {0.f, 0.f, 0.f, 0.f};
            if (bm + row < M)
                v = *reinterpret_cast<const float4*>(&x[(size_t)(bm + row) * D + k0 + q * 4]);
            u16x4 pk = {f2bf(v.x), f2bf(v.y), f2bf(v.z), f2bf(v.w)};
            *reinterpret_cast<u16x4*>(&xs[row][q * 4]) = pk;
        }
        #pragma unroll
        for (int p = 0; p < 4; ++p) {
            const int row = srow + p * 32;
            u16x4 v = *reinterpret_cast<const u16x4*>(&Wt[(size_t)(bn + row) * D + k0 + q * 4]);
            *reinterpret_cast<u16x4*>(&ws[row][q * 4]) = v;
        }
        __syncthreads();

        s16x8 af[4], bf[4];
        #pragma unroll
        for (int fi = 0; fi < 4; ++fi)
            af[fi] = *reinterpret_cast<const s16x8*>(&ws[wn * 64 + fi * 16 + l15][l4 * 8]);
        #pragma unroll
        for (int fj = 0; fj < 4; ++fj)
            bf[fj] = *reinterpret_cast<const s16x8*>(&xs[wm * 64 + fj * 16 + l15][l4 * 8]);
        #pragma unroll
        for (int fi = 0; fi < 4; ++fi)
            #pragma unroll
            for (int fj = 0; fj < 4; ++fj)
                acc[fi][fj] = __builtin_amdgcn_mfma_f32_16x16x32_bf16(af[fi], bf[fj], acc[fi][fj], 0, 0, 0);
        __syncthreads();
    }

    #pragma unroll
    for (int fj = 0; fj < 4; ++fj) {
        const int m = bm + wm * 64 + fj * 16 + l15;
        if (m >= M) continue;
        #pragma unroll
        for (int fi = 0; fi < 4; ++fi) {
            const int n = bn + wn * 64 + fi * 16 + l4 * 4;
            u16x4 pk = {f2bf(acc[fi][fj][0]), f2bf(acc[fi][fj][1]),
                        f2bf(acc[fi][fj][2]), f2bf(acc[fi][fj][3])};
            *reinterpret_cast<u16x4*>(&h[(size_t)m * D + n]) = pk;
        }
    }
}

// ---------------- finalize: per bucket, ELL-ize ----------------
__global__ __launch_bounds__(256) void k_finalize(const int2* __restrict__ eds,
                                                  const int* __restrict__ bucketStart,
                                                  int2* __restrict__ pairs,
                                                  int* __restrict__ cnt, int N) {
    __shared__ int cur[256];
    const int b = blockIdx.x;
    const int t = threadIdx.x;
    cur[t] = 0;
    __syncthreads();
    const int lo = bucketStart[b], hi = bucketStart[b + 1];
    for (int i = lo + t; i < hi; i += 256) {
        const int2 p = eds[i];
        const int low8 = ((unsigned)p.x) >> 24;
        const int r = atomicAdd(&cur[low8], 1);
        if (r < CAP) {
            const int node = (b << 8) | low8;
            pairs[(size_t)node * CAP + r] = make_int2(p.x & 0x00FFFFFF, p.y);
        }
    }
    __syncthreads();
    const int node = (b << 8) | t;
    if (node < N) cnt[node] = cur[t] < CAP ? cur[t] : CAP;
}

// ---------------- sliced gather: slice s (32 cols, 3.2MB of h) pinned to XCD s ----------------
// Block claims (slice, group) from per-slice counters, preferring its own XCD's
// slice. Claim cascade guarantees every slot is processed exactly once
// regardless of the XCC_ID mapping. 8 threads per node, 4 cols per thread,
// register accumulation, fused bias+relu.
__global__ __launch_bounds__(256) void gather_sliced(const int2* __restrict__ pairs,
                                                     const int* __restrict__ cnt,
                                                     const unsigned short* __restrict__ h,
                                                     const float* __restrict__ bias,
                                                     float* __restrict__ z,
                                                     int N, int ngroups,
                                                     int* __restrict__ claim) {
    __shared__ int sS, sG;
    if (threadIdx.x == 0) {
        const int pref = xcc_id();
        int s = -1, g = -1;
        for (int ds = 0; ds < 8; ++ds) {
            const int ss = (pref + ds) & 7;
            const int gg = atomicAdd(&claim[ss * 32], 1);   // 128B-spaced counters
            if (gg < ngroups) { s = ss; g = gg; break; }
        }
        sS = s; sG = g;
    }
    __syncthreads();
    const int slice = sS;
    if (slice < 0) return;
    const int node = sG * 32 + ((int)threadIdx.x >> 3);
    if (node >= N) return;
    const int t8 = threadIdx.x & 7;
    const int col = slice * 32 + t8 * 4;
    const int dg = cnt[node];
    const int2* pr = pairs + (size_t)node * CAP;
    const unsigned short* hc = h + col;

    float4 acc = {0.f, 0.f, 0.f, 0.f};
    int e = 0;
    for (; e + 4 <= dg; e += 4) {
        const int2 p0 = pr[e];
        const int2 p1 = pr[e + 1];
        const int2 p2 = pr[e + 2];
        const int2 p3 = pr[e + 3];
        const uint2 a0 = *reinterpret_cast<const uint2*>(hc + (size_t)p0.x * D);
        const uint2 a1 = *reinterpret_cast<const uint2*>(hc + (size_t)p1.x * D);
        const uint2 a2 = *reinterpret_cast<const uint2*>(hc + (size_t)p2.x * D);
        const uint2 a3 = *reinterpret_cast<const uint2*>(hc + (size_t)p3.x * D);
        const float v0 = __int_as_float(p0.y);
        const float v1 = __int_as_float(p1.y);
        const float v2 = __int_as_float(p2.y);
        const float v3 = __int_as_float(p3.y);
        acc.x = fmaf(v0, __uint_as_float(a0.x << 16), acc.x);
        acc.y = fmaf(v0, __uint_as_float(a0.x & 0xffff0000u), acc.y);
        acc.z = fmaf(v0, __uint_as_float(a0.y << 16), acc.z);
        acc.w = fmaf(v0, __uint_as_float(a0.y & 0xffff0000u), acc.w);
        acc.x = fmaf(v1, __uint_as_float(a1.x << 16), acc.x);
        acc.y = fmaf(v1, __uint_as_float(a1.x & 0xffff0000u), acc.y);
        acc.z = fmaf(v1, __uint_as_float(a1.y << 16), acc.z);
        acc.w = fmaf(v1, __uint_as_float(a1.y & 0xffff0000u), acc.w);
        acc.x = fmaf(v2, __uint_as_float(a2.x << 16), acc.x);
        acc.y = fmaf(v2, __uint_as_float(a2.x & 0xffff0000u), acc.y);
        acc.z = fmaf(v2, __uint_as_float(a2.y << 16), acc.z);
        acc.w = fmaf(v2, __uint_as_float(a2.y & 0xffff0000u), acc.w);
        acc.x = fmaf(v3, __uint_as_float(a3.x << 16), acc.x);
        acc.y = fmaf(v3, __uint_as_float(a3.x & 0xffff0000u), acc.y);
        acc.z = fmaf(v3, __uint_as_float(a3.y << 16), acc.z);
        acc.w = fmaf(v3, __uint_as_float(a3.y & 0xffff0000u), acc.w);
    }
    for (; e < dg; ++e) {
        const int2 p0 = pr[e];
        const float v0 = __int_as_float(p0.y);
        const uint2 a0 = *reinterpret_cast<const uint2*>(hc + (size_t)p0.x * D);
        acc.x = fmaf(v0, __uint_as_float(a0.x << 16), acc.x);
        acc.y = fmaf(v0, __uint_as_float(a0.x & 0xffff0000u), acc.y);
        acc.z = fmaf(v0, __uint_as_float(a0.y << 16), acc.z);
        acc.w = fmaf(v0, __uint_as_float(a0.y & 0xffff0000u), acc.w);
    }

    const float4 bb = *reinterpret_cast<const float4*>(bias + col);
    acc.x = fmaxf(acc.x + bb.x, 0.f);
    acc.y = fmaxf(acc.y + bb.y, 0.f);
    acc.z = fmaxf(acc.z + bb.z, 0.f);
    acc.w = fmaxf(acc.w + bb.w, 0.f);
    *reinterpret_cast<float4*>(z + (size_t)node * D + col) = acc;
}

extern "C" void kernel_launch(void* const* d_in, const int* in_sizes, int n_in,
                              void* d_out, int out_size, void* d_ws, size_t ws_size,
                              hipStream_t stream) {
    const int*   edge_src = (const int*)d_in[0];
    const int*   edge_dst = (const int*)d_in[1];
    const float* edge_val = (const float*)d_in[2];
    const float* x        = (const float*)d_in[3];
    const float* W        = (const float*)d_in[4];
    const float* b        = (const float*)d_in[5];

    const int E = in_sizes[0];
    const int N = in_sizes[3] / D;
    const int nch = (E + CHUNK - 1) / CHUNK;   // 196
    const int nb  = (N + 255) >> 8;            // 196 (<= 256)
    const int ngroups = (N + 31) / 32;         // 1563

    float* z = (float*)d_out;

    // workspace layout (~58.2 MB); eds de-aliased from h (concurrent in k_main)
    unsigned short* h     = (unsigned short*)d_ws;                      // N*D bf16 (25.6 MB)
    int2*           pairs = (int2*)(h + (size_t)N * D);                 // N*CAP int2 (25.6 MB)
    int2*           eds   = pairs + (size_t)N * CAP;                    // E int2 (6.4 MB)
    unsigned short* Wt    = (unsigned short*)(eds + E);                 // 128 KB
    int* partial     = (int*)(Wt + D * D);                              // nb*nch
    int* bucketStart = partial + nb * nch;                              // nb+1
    int* cnt         = bucketStart + (nb + 1);                          // N      (zeroed)
    int* claim       = cnt + N;                                         // 256    (zeroed)
    int* rowSum      = claim + 256;                                     // nb     (zeroed)

    hipMemsetAsync(cnt, 0, (size_t)(N + 256 + nb) * sizeof(int), stream);

    k_prep<<<256 + nch, 256, 0, stream>>>(W, Wt, edge_dst, partial, rowSum, E, nch, nb);

    const int nscan = (nb + 3) / 4;
    k_scan<<<nscan + 1, 256, 0, stream>>>(partial, rowSum, bucketStart, nch, nb, nscan);

    const int gridM = (N + BMT - 1) / BMT;
    k_main<<<nch + gridM * 2, 256, 0, stream>>>(edge_src, edge_dst, edge_val, partial,
                                                bucketStart, eds, E, nch, nb,
                                                x, Wt, h, N);

    k_finalize<<<nb, 256, 0, stream>>>(eds, bucketStart, pairs, cnt, N);

    gather_sliced<<<8 * ngroups, 256, 0, stream>>>(pairs, cnt, h, b, z, N, ngroups, claim);
}

// Round 8
// 123.478 us; speedup vs baseline: 1.3563x; 1.3563x over previous
//
#include <hip/hip_runtime.h>

#define D 256     // D_IN == D_OUT == 256
#define CAP 64    // ELL row capacity (deg ~ Poisson(16); P(>64) ~ 0)
#define CHUNK 4096
#define BMT 64    // gemm m-tile
#define BK 32
#define PK 40     // padded LDS k-stride (bf16): 80B, good bank spread

typedef __attribute__((ext_vector_type(4))) float f32x4;
typedef __attribute__((ext_vector_type(8))) short s16x8;
typedef __attribute__((ext_vector_type(4))) unsigned short u16x4;

static __device__ __forceinline__ unsigned short f2bf(float f) {
    unsigned int u = __float_as_uint(f);
    unsigned int r = (u + 0x7fffu + ((u >> 16) & 1u)) >> 16;  // RTNE
    return (unsigned short)r;
}

// ---------------- Stage A: transpose_w (blocks 0..255) ∥ hist (blocks 256..) ----------------
__global__ __launch_bounds__(256) void k_prep(const float* __restrict__ W,
                                              unsigned short* __restrict__ Wt,
                                              const int* __restrict__ dst,
                                              int* __restrict__ partial,
                                              int* __restrict__ rowSum,
                                              int E, int nch, int nb) {
    __shared__ float s[16][17];
    __shared__ int lh[256];
    const int t = threadIdx.x;
    if ((int)blockIdx.x < 256) {
        const int lk = t & 15, ln = t >> 4;
        const int k0 = ((int)blockIdx.x & 15) * 16;
        const int n0 = ((int)blockIdx.x >> 4) * 16;
        s[ln][lk] = W[(k0 + ln) * D + n0 + lk];
        __syncthreads();
        Wt[(n0 + ln) * D + k0 + lk] = f2bf(s[lk][ln]);
        return;
    }
    const int c = (int)blockIdx.x - 256;
    lh[t] = 0;
    __syncthreads();
    const int base = c * CHUNK;
    for (int k = 0; k < CHUNK; k += 256) {
        const int e = base + k + t;
        if (e < E) atomicAdd(&lh[dst[e] >> 8], 1);
    }
    __syncthreads();
    if (t < nb) {
        partial[t * nch + c] = lh[t];
        if (lh[t]) atomicAdd(&rowSum[t], lh[t]);
    }
}

// ---------------- Stage B: rowscan (blocks < nscan) ∥ bstart (last block) ----------------
__global__ __launch_bounds__(256) void k_scan(int* __restrict__ partial,
                                              const int* __restrict__ rowSum,
                                              int* __restrict__ bucketStart,
                                              int nch, int nb, int nscan) {
    if ((int)blockIdx.x < nscan) {
        const int bkt = blockIdx.x * 4 + (threadIdx.x >> 6);
        if (bkt >= nb) return;
        const int lane = threadIdx.x & 63;
        int running = 0;
        for (int k = 0; k < nch; k += 64) {
            const int idx = k + lane;
            int v = (idx < nch) ? partial[bkt * nch + idx] : 0;
            int incl = v;
            #pragma unroll
            for (int sft = 1; sft < 64; sft <<= 1) {
                const int u = __shfl_up(incl, sft, 64);
                if (lane >= sft) incl += u;
            }
            if (idx < nch) partial[bkt * nch + idx] = running + incl - v;
            running += __shfl(incl, 63, 64);
        }
        return;
    }
    __shared__ int wsum[4];
    const int t = threadIdx.x;
    const int lane = t & 63;
    const int w = t >> 6;
    const int v = (t < nb) ? rowSum[t] : 0;
    int incl = v;
    #pragma unroll
    for (int sft = 1; sft < 64; sft <<= 1) {
        const int u = __shfl_up(incl, sft, 64);
        if (lane >= sft) incl += u;
    }
    if (lane == 63) wsum[w] = incl;
    __syncthreads();
    if (t == 0) {
        int acc = 0;
        for (int i = 0; i < 4; ++i) { const int u = wsum[i]; wsum[i] = acc; acc += u; }
    }
    __syncthreads();
    const int ex = incl - v + wsum[w];
    if (t <= nb) bucketStart[t] = ex;
}

// ---------------- Stage C: scatter (blocks < nch) ∥ GEMM 64x256 (rest) ----------------
__global__ __launch_bounds__(256) void k_main(
    const int* __restrict__ src, const int* __restrict__ dstp,
    const float* __restrict__ val, const int* __restrict__ partial,
    const int* __restrict__ bucketStart, int2* __restrict__ eds,
    int E, int nch, int nb,
    const float* __restrict__ x, const unsigned short* __restrict__ Wt,
    unsigned short* __restrict__ h, int M) {

    __shared__ unsigned short ws[256][PK];  // Wt tile: [n][k]  (20 KB)
    __shared__ unsigned short xs[BMT][PK];  // x  tile: [m][k]  (5 KB)
    __shared__ int cur[256];
    const int t = threadIdx.x;

    if ((int)blockIdx.x < nch) {
        const int c = blockIdx.x;
        if (t < nb) cur[t] = bucketStart[t] + partial[t * nch + c];
        __syncthreads();
        const int base = c * CHUNK;
        for (int k = 0; k < CHUNK; k += 256) {
            const int e = base + k + t;
            if (e < E) {
                const int d = dstp[e];
                const int sv = src[e];
                const float v = val[e];
                const int pos = atomicAdd(&cur[d >> 8], 1);
                eds[pos] = make_int2(sv | ((d & 255) << 24), __float_as_int(v));
            }
        }
        return;
    }

    // ---- GEMM: tile 64(m) x 256(n), K-loop over D ----
    const int bm = ((int)blockIdx.x - nch) * BMT;
    const int lane = t & 63;
    const int w    = t >> 6;      // wave = n-quarter
    const int l15  = lane & 15;
    const int l4   = lane >> 4;
    const int xrow = t >> 2;      // 0..63
    const int q    = t & 3;       // k-chunk of 8

    f32x4 acc[4][4] = {};

    for (int k0 = 0; k0 < D; k0 += BK) {
        // stage x tile [64 m][32 k] fp32->bf16: thread loads 8 elems (2 float4)
        {
            float4 v0 = {0.f, 0.f, 0.f, 0.f}, v1 = {0.f, 0.f, 0.f, 0.f};
            if (bm + xrow < M) {
                const float* px = &x[(size_t)(bm + xrow) * D + k0 + q * 8];
                v0 = *reinterpret_cast<const float4*>(px);
                v1 = *reinterpret_cast<const float4*>(px + 4);
            }
            u16x4 p0 = {f2bf(v0.x), f2bf(v0.y), f2bf(v0.z), f2bf(v0.w)};
            u16x4 p1 = {f2bf(v1.x), f2bf(v1.y), f2bf(v1.z), f2bf(v1.w)};
            *reinterpret_cast<u16x4*>(&xs[xrow][q * 8])     = p0;
            *reinterpret_cast<u16x4*>(&xs[xrow][q * 8 + 4]) = p1;
        }
        // stage Wt tile [256 n][32 k] bf16: 4 rows/thread, 16B loads
        #pragma unroll
        for (int p = 0; p < 4; ++p) {
            const int row = (t >> 2) + p * 64;
            u16x4 v = *reinterpret_cast<const u16x4*>(&Wt[(size_t)row * D + k0 + q * 8]);
            u16x4 v2 = *reinterpret_cast<const u16x4*>(&Wt[(size_t)row * D + k0 + q * 8 + 4]);
            *reinterpret_cast<u16x4*>(&ws[row][q * 8])     = v;
            *reinterpret_cast<u16x4*>(&ws[row][q * 8 + 4]) = v2;
        }
        __syncthreads();

        s16x8 af[4], bf[4];
        #pragma unroll
        for (int fi = 0; fi < 4; ++fi)
            af[fi] = *reinterpret_cast<const s16x8*>(&ws[w * 64 + fi * 16 + l15][l4 * 8]);
        #pragma unroll
        for (int fj = 0; fj < 4; ++fj)
            bf[fj] = *reinterpret_cast<const s16x8*>(&xs[fj * 16 + l15][l4 * 8]);
        #pragma unroll
        for (int fi = 0; fi < 4; ++fi)
            #pragma unroll
            for (int fj = 0; fj < 4; ++fj)
                acc[fi][fj] = __builtin_amdgcn_mfma_f32_16x16x32_bf16(af[fi], bf[fj], acc[fi][fj], 0, 0, 0);
        __syncthreads();
    }

    #pragma unroll
    for (int fj = 0; fj < 4; ++fj) {
        const int m = bm + fj * 16 + l15;
        if (m >= M) continue;
        #pragma unroll
        for (int fi = 0; fi < 4; ++fi) {
            const int n = w * 64 + fi * 16 + l4 * 4;
            u16x4 pk = {f2bf(acc[fi][fj][0]), f2bf(acc[fi][fj][1]),
                        f2bf(acc[fi][fj][2]), f2bf(acc[fi][fj][3])};
            *reinterpret_cast<u16x4*>(&h[(size_t)m * D + n]) = pk;
        }
    }
}

// ---------------- finalize: per bucket, ELL-ize ----------------
__global__ __launch_bounds__(256) void k_finalize(const int2* __restrict__ eds,
                                                  const int* __restrict__ bucketStart,
                                                  int2* __restrict__ pairs,
                                                  int* __restrict__ cnt, int N) {
    __shared__ int cur[256];
    const int b = blockIdx.x;
    const int t = threadIdx.x;
    cur[t] = 0;
    __syncthreads();
    const int lo = bucketStart[b], hi = bucketStart[b + 1];
    for (int i = lo + t; i < hi; i += 256) {
        const int2 p = eds[i];
        const int low8 = ((unsigned)p.x) >> 24;
        const int r = atomicAdd(&cur[low8], 1);
        if (r < CAP) {
            const int node = (b << 8) | low8;
            pairs[(size_t)node * CAP + r] = make_int2(p.x & 0x00FFFFFF, p.y);
        }
    }
    __syncthreads();
    const int node = (b << 8) | t;
    if (node < N) cnt[node] = cur[t] < CAP ? cur[t] : CAP;
}

// ---------------- Gather: z[n] = relu(b + sum_e val * h_bf16[src]) ----------------
__global__ __launch_bounds__(256) void gather_csr(const int2* __restrict__ pairs,
                                                  const int* __restrict__ cnt,
                                                  const unsigned short* __restrict__ h,
                                                  const float* __restrict__ b,
                                                  float* __restrict__ z, int N) {
    const int node = blockIdx.x * 4 + (threadIdx.x >> 6);
    if (node >= N) return;
    const int lane = threadIdx.x & 63;
    const size_t o = (size_t)node * CAP;
    const int dg = cnt[node];

    float4 acc = {0.f, 0.f, 0.f, 0.f};
    int e = 0;
    for (; e + 4 <= dg; e += 4) {
        const int2 p0 = pairs[o + e];
        const int2 p1 = pairs[o + e + 1];
        const int2 p2 = pairs[o + e + 2];
        const int2 p3 = pairs[o + e + 3];
        const uint2 h0 = *reinterpret_cast<const uint2*>(&h[(size_t)p0.x * D + lane * 4]);
        const uint2 h1 = *reinterpret_cast<const uint2*>(&h[(size_t)p1.x * D + lane * 4]);
        const uint2 h2 = *reinterpret_cast<const uint2*>(&h[(size_t)p2.x * D + lane * 4]);
        const uint2 h3 = *reinterpret_cast<const uint2*>(&h[(size_t)p3.x * D + lane * 4]);
        const float v0 = __int_as_float(p0.y);
        const float v1 = __int_as_float(p1.y);
        const float v2 = __int_as_float(p2.y);
        const float v3 = __int_as_float(p3.y);
        acc.x = fmaf(v0, __uint_as_float(h0.x << 16), acc.x);
        acc.y = fmaf(v0, __uint_as_float(h0.x & 0xffff0000u), acc.y);
        acc.z = fmaf(v0, __uint_as_float(h0.y << 16), acc.z);
        acc.w = fmaf(v0, __uint_as_float(h0.y & 0xffff0000u), acc.w);
        acc.x = fmaf(v1, __uint_as_float(h1.x << 16), acc.x);
        acc.y = fmaf(v1, __uint_as_float(h1.x & 0xffff0000u), acc.y);
        acc.z = fmaf(v1, __uint_as_float(h1.y << 16), acc.z);
        acc.w = fmaf(v1, __uint_as_float(h1.y & 0xffff0000u), acc.w);
        acc.x = fmaf(v2, __uint_as_float(h2.x << 16), acc.x);
        acc.y = fmaf(v2, __uint_as_float(h2.x & 0xffff0000u), acc.y);
        acc.z = fmaf(v2, __uint_as_float(h2.y << 16), acc.z);
        acc.w = fmaf(v2, __uint_as_float(h2.y & 0xffff0000u), acc.w);
        acc.x = fmaf(v3, __uint_as_float(h3.x << 16), acc.x);
        acc.y = fmaf(v3, __uint_as_float(h3.x & 0xffff0000u), acc.y);
        acc.z = fmaf(v3, __uint_as_float(h3.y << 16), acc.z);
        acc.w = fmaf(v3, __uint_as_float(h3.y & 0xffff0000u), acc.w);
    }
    for (; e < dg; ++e) {
        const int2 p0 = pairs[o + e];
        const float v0 = __int_as_float(p0.y);
        const uint2 h0 = *reinterpret_cast<const uint2*>(&h[(size_t)p0.x * D + lane * 4]);
        acc.x = fmaf(v0, __uint_as_float(h0.x << 16), acc.x);
        acc.y = fmaf(v0, __uint_as_float(h0.x & 0xffff0000u), acc.y);
        acc.z = fmaf(v0, __uint_as_float(h0.y << 16), acc.z);
        acc.w = fmaf(v0, __uint_as_float(h0.y & 0xffff0000u), acc.w);
    }

    const float4 bb = *reinterpret_cast<const float4*>(&b[lane * 4]);
    acc.x = fmaxf(acc.x + bb.x, 0.f);
    acc.y = fmaxf(acc.y + bb.y, 0.f);
    acc.z = fmaxf(acc.z + bb.z, 0.f);
    acc.w = fmaxf(acc.w + bb.w, 0.f);
    *reinterpret_cast<float4*>(&z[(size_t)node * D + lane * 4]) = acc;
}

extern "C" void kernel_launch(void* const* d_in, const int* in_sizes, int n_in,
                              void* d_out, int out_size, void* d_ws, size_t ws_size,
                              hipStream_t stream) {
    const int*   edge_src = (const int*)d_in[0];
    const int*   edge_dst = (const int*)d_in[1];
    const float* edge_val = (const float*)d_in[2];
    const float* x        = (const float*)d_in[3];
    const float* W        = (const float*)d_in[4];
    const float* b        = (const float*)d_in[5];

    const int E = in_sizes[0];
    const int N = in_sizes[3] / D;
    const int nch = (E + CHUNK - 1) / CHUNK;   // 196
    const int nb  = (N + 255) >> 8;            // 196 (<= 256)

    float* z = (float*)d_out;

    // workspace layout (~58 MB)
    unsigned short* h     = (unsigned short*)d_ws;                      // N*D bf16 (25.6 MB)
    int2*           pairs = (int2*)(h + (size_t)N * D);                 // N*CAP int2 (25.6 MB)
    int2*           eds   = pairs + (size_t)N * CAP;                    // E int2 (6.4 MB)
    unsigned short* Wt    = (unsigned short*)(eds + E);                 // 128 KB
    int* partial     = (int*)(Wt + D * D);                              // nb*nch
    int* bucketStart = partial + nb * nch;                              // nb+1
    int* cnt         = bucketStart + (nb + 1);                          // N (written fully by finalize)
    int* rowSum      = cnt + N;                                         // nb (must be zeroed)

    hipMemsetAsync(rowSum, 0, (size_t)nb * sizeof(int), stream);

    k_prep<<<256 + nch, 256, 0, stream>>>(W, Wt, edge_dst, partial, rowSum, E, nch, nb);

    const int nscan = (nb + 3) / 4;
    k_scan<<<nscan + 1, 256, 0, stream>>>(partial, rowSum, bucketStart, nch, nb, nscan);

    const int gridM = (N + BMT - 1) / BMT;   // 782
    k_main<<<nch + gridM, 256, 0, stream>>>(edge_src, edge_dst, edge_val, partial,
                                            bucketStart, eds, E, nch, nb,
                                            x, Wt, h, N);

    k_finalize<<<nb, 256, 0, stream>>>(eds, bucketStart, pairs, cnt, N);

    gather_csr<<<(N + 3) / 4, 256, 0, stream>>>(pairs, cnt, h, b, z, N);
}

// Round 9
// 119.019 us; speedup vs baseline: 1.4071x; 1.0375x over previous
//
#include <hip/hip_runtime.h>

#define D 256     // D_IN == D_OUT == 256
#define CAP 64    // ELL row capacity (deg ~ Poisson(16); P(>64) ~ 0)
#define CHUNK 4096
#define BMT 64    // gemm m-tile
#define BK 32
#define PK 40     // padded LDS k-stride (bf16)

typedef __attribute__((ext_vector_type(4))) float f32x4;
typedef __attribute__((ext_vector_type(8))) short s16x8;
typedef __attribute__((ext_vector_type(4))) unsigned short u16x4;

static __device__ __forceinline__ unsigned short f2bf(float f) {
    unsigned int u = __float_as_uint(f);
    unsigned int r = (u + 0x7fffu + ((u >> 16) & 1u)) >> 16;  // RTNE
    return (unsigned short)r;
}

// ---------------- GEMM block body: 64(m) x 256(n) tile, bf16 MFMA ----------------
static __device__ __forceinline__ void gemm_block(
    int bm, unsigned short (*ws)[PK], unsigned short (*xs)[PK],
    const float* __restrict__ x, const unsigned short* __restrict__ Wt,
    unsigned short* __restrict__ h, int M, int t) {
    const int lane = t & 63;
    const int w    = t >> 6;      // wave = n-quarter
    const int l15  = lane & 15;
    const int l4   = lane >> 4;
    const int xrow = t >> 2;      // 0..63
    const int q    = t & 3;       // k-chunk of 8

    f32x4 acc[4][4] = {};

    for (int k0 = 0; k0 < D; k0 += BK) {
        {
            float4 v0 = {0.f, 0.f, 0.f, 0.f}, v1 = {0.f, 0.f, 0.f, 0.f};
            if (bm + xrow < M) {
                const float* px = &x[(size_t)(bm + xrow) * D + k0 + q * 8];
                v0 = *reinterpret_cast<const float4*>(px);
                v1 = *reinterpret_cast<const float4*>(px + 4);
            }
            u16x4 p0 = {f2bf(v0.x), f2bf(v0.y), f2bf(v0.z), f2bf(v0.w)};
            u16x4 p1 = {f2bf(v1.x), f2bf(v1.y), f2bf(v1.z), f2bf(v1.w)};
            *reinterpret_cast<u16x4*>(&xs[xrow][q * 8])     = p0;
            *reinterpret_cast<u16x4*>(&xs[xrow][q * 8 + 4]) = p1;
        }
        #pragma unroll
        for (int p = 0; p < 4; ++p) {
            const int row = (t >> 2) + p * 64;
            u16x4 v  = *reinterpret_cast<const u16x4*>(&Wt[(size_t)row * D + k0 + q * 8]);
            u16x4 v2 = *reinterpret_cast<const u16x4*>(&Wt[(size_t)row * D + k0 + q * 8 + 4]);
            *reinterpret_cast<u16x4*>(&ws[row][q * 8])     = v;
            *reinterpret_cast<u16x4*>(&ws[row][q * 8 + 4]) = v2;
        }
        __syncthreads();

        s16x8 af[4], bf[4];
        #pragma unroll
        for (int fi = 0; fi < 4; ++fi)
            af[fi] = *reinterpret_cast<const s16x8*>(&ws[w * 64 + fi * 16 + l15][l4 * 8]);
        #pragma unroll
        for (int fj = 0; fj < 4; ++fj)
            bf[fj] = *reinterpret_cast<const s16x8*>(&xs[fj * 16 + l15][l4 * 8]);
        #pragma unroll
        for (int fi = 0; fi < 4; ++fi)
            #pragma unroll
            for (int fj = 0; fj < 4; ++fj)
                acc[fi][fj] = __builtin_amdgcn_mfma_f32_16x16x32_bf16(af[fi], bf[fj], acc[fi][fj], 0, 0, 0);
        __syncthreads();
    }

    #pragma unroll
    for (int fj = 0; fj < 4; ++fj) {
        const int m = bm + fj * 16 + l15;
        if (m >= M) continue;
        #pragma unroll
        for (int fi = 0; fi < 4; ++fi) {
            const int n = w * 64 + fi * 16 + l4 * 4;
            u16x4 pk = {f2bf(acc[fi][fj][0]), f2bf(acc[fi][fj][1]),
                        f2bf(acc[fi][fj][2]), f2bf(acc[fi][fj][3])};
            *reinterpret_cast<u16x4*>(&h[(size_t)m * D + n]) = pk;
        }
    }
}

// ---------------- Stage A: transpose_w (blocks 0..255) ∥ hist int4 (blocks 256..) ----------------
__global__ __launch_bounds__(256) void k_prep(const float* __restrict__ W,
                                              unsigned short* __restrict__ Wt,
                                              const int* __restrict__ dst,
                                              int* __restrict__ partial,
                                              int* __restrict__ rowSum,
                                              int E, int nch, int nb) {
    __shared__ float s[16][17];
    __shared__ int lh[256];
    const int t = threadIdx.x;
    if ((int)blockIdx.x < 256) {
        const int lk = t & 15, ln = t >> 4;
        const int k0 = ((int)blockIdx.x & 15) * 16;
        const int n0 = ((int)blockIdx.x >> 4) * 16;
        s[ln][lk] = W[(k0 + ln) * D + n0 + lk];
        __syncthreads();
        Wt[(n0 + ln) * D + k0 + lk] = f2bf(s[lk][ln]);
        return;
    }
    const int c = (int)blockIdx.x - 256;
    lh[t] = 0;
    __syncthreads();
    #pragma unroll
    for (int p = 0; p < CHUNK / 1024; ++p) {
        const int i4 = c * (CHUNK / 4) + p * 256 + t;
        const int e = i4 << 2;
        if (e + 3 < E) {
            const int4 d4 = reinterpret_cast<const int4*>(dst)[i4];
            atomicAdd(&lh[d4.x >> 8], 1);
            atomicAdd(&lh[d4.y >> 8], 1);
            atomicAdd(&lh[d4.z >> 8], 1);
            atomicAdd(&lh[d4.w >> 8], 1);
        } else {
            for (int j = e; j < E; ++j) atomicAdd(&lh[dst[j] >> 8], 1);
        }
    }
    __syncthreads();
    if (t < nb) {
        partial[t * nch + c] = lh[t];
        if (lh[t]) atomicAdd(&rowSum[t], lh[t]);
    }
}

// ---------------- Stage B: rowscan (blocks < nscan) ∥ bstart (last block) ----------------
__global__ __launch_bounds__(256) void k_scan(int* __restrict__ partial,
                                              const int* __restrict__ rowSum,
                                              int* __restrict__ bucketStart,
                                              int nch, int nb, int nscan) {
    if ((int)blockIdx.x < nscan) {
        const int bkt = blockIdx.x * 4 + (threadIdx.x >> 6);
        if (bkt >= nb) return;
        const int lane = threadIdx.x & 63;
        int running = 0;
        for (int k = 0; k < nch; k += 64) {
            const int idx = k + lane;
            int v = (idx < nch) ? partial[bkt * nch + idx] : 0;
            int incl = v;
            #pragma unroll
            for (int sft = 1; sft < 64; sft <<= 1) {
                const int u = __shfl_up(incl, sft, 64);
                if (lane >= sft) incl += u;
            }
            if (idx < nch) partial[bkt * nch + idx] = running + incl - v;
            running += __shfl(incl, 63, 64);
        }
        return;
    }
    __shared__ int wsum[4];
    const int t = threadIdx.x;
    const int lane = t & 63;
    const int w = t >> 6;
    const int v = (t < nb) ? rowSum[t] : 0;
    int incl = v;
    #pragma unroll
    for (int sft = 1; sft < 64; sft <<= 1) {
        const int u = __shfl_up(incl, sft, 64);
        if (lane >= sft) incl += u;
    }
    if (lane == 63) wsum[w] = incl;
    __syncthreads();
    if (t == 0) {
        int acc = 0;
        for (int i = 0; i < 4; ++i) { const int u = wsum[i]; wsum[i] = acc; acc += u; }
    }
    __syncthreads();
    const int ex = incl - v + wsum[w];
    if (t <= nb) bucketStart[t] = ex;
}

// ---------------- Stage C1: scatter (blocks < nch) ∥ GEMM part A ----------------
__global__ __launch_bounds__(256) void k_mainA(
    const int* __restrict__ src, const int* __restrict__ dstp,
    const float* __restrict__ val, const int* __restrict__ partial,
    const int* __restrict__ bucketStart, int2* __restrict__ eds,
    int E, int nch, int nb,
    const float* __restrict__ x, const unsigned short* __restrict__ Wt,
    unsigned short* __restrict__ h, int M) {

    __shared__ unsigned short ws[256][PK];
    __shared__ unsigned short xs[BMT][PK];
    __shared__ int cur[256];
    const int t = threadIdx.x;

    if ((int)blockIdx.x < nch) {
        const int c = blockIdx.x;
        if (t < nb) cur[t] = bucketStart[t] + partial[t * nch + c];
        __syncthreads();
        #pragma unroll
        for (int p = 0; p < CHUNK / 1024; ++p) {
            const int i4 = c * (CHUNK / 4) + p * 256 + t;
            const int e = i4 << 2;
            if (e + 3 < E) {
                const int4   s4 = reinterpret_cast<const int4*>(src)[i4];
                const int4   d4 = reinterpret_cast<const int4*>(dstp)[i4];
                const float4 v4 = reinterpret_cast<const float4*>(val)[i4];
                const int p0 = atomicAdd(&cur[d4.x >> 8], 1);
                const int p1 = atomicAdd(&cur[d4.y >> 8], 1);
                const int p2 = atomicAdd(&cur[d4.z >> 8], 1);
                const int p3 = atomicAdd(&cur[d4.w >> 8], 1);
                eds[p0] = make_int2(s4.x | ((d4.x & 255) << 24), __float_as_int(v4.x));
                eds[p1] = make_int2(s4.y | ((d4.y & 255) << 24), __float_as_int(v4.y));
                eds[p2] = make_int2(s4.z | ((d4.z & 255) << 24), __float_as_int(v4.z));
                eds[p3] = make_int2(s4.w | ((d4.w & 255) << 24), __float_as_int(v4.w));
            } else {
                for (int j = e; j < E; ++j) {
                    const int d = dstp[j];
                    const int pos = atomicAdd(&cur[d >> 8], 1);
                    eds[pos] = make_int2(src[j] | ((d & 255) << 24), __float_as_int(val[j]));
                }
            }
        }
        return;
    }

    gemm_block(((int)blockIdx.x - nch) * BMT, ws, xs, x, Wt, h, M, t);
}

// ---------------- Stage C2: finalize (blocks < nb) ∥ GEMM part B ----------------
__global__ __launch_bounds__(256) void k_mainB(
    const int2* __restrict__ eds, const int* __restrict__ bucketStart,
    int2* __restrict__ pairs, int* __restrict__ cnt, int N, int nb,
    const float* __restrict__ x, const unsigned short* __restrict__ Wt,
    unsigned short* __restrict__ h, int M, int gAoff) {

    __shared__ unsigned short ws[256][PK];
    __shared__ unsigned short xs[BMT][PK];
    __shared__ int cur[256];
    const int t = threadIdx.x;

    if ((int)blockIdx.x < nb) {
        const int b = blockIdx.x;
        cur[t] = 0;
        __syncthreads();
        const int lo = bucketStart[b], hi = bucketStart[b + 1];
        for (int i = lo + t; i < hi; i += 256) {
            const int2 p = eds[i];
            const int low8 = ((unsigned)p.x) >> 24;
            const int r = atomicAdd(&cur[low8], 1);
            if (r < CAP) {
                const int node = (b << 8) | low8;
                pairs[(size_t)node * CAP + r] = make_int2(p.x & 0x00FFFFFF, p.y);
            }
        }
        __syncthreads();
        const int node = (b << 8) | t;
        if (node < N) cnt[node] = cur[t] < CAP ? cur[t] : CAP;
        return;
    }

    gemm_block((gAoff + (int)blockIdx.x - nb) * BMT, ws, xs, x, Wt, h, M, t);
}

// ---------------- Gather: z[n] = relu(b + sum_e val * h_bf16[src]) ----------------
__global__ __launch_bounds__(256) void gather_csr(const int2* __restrict__ pairs,
                                                  const int* __restrict__ cnt,
                                                  const unsigned short* __restrict__ h,
                                                  const float* __restrict__ b,
                                                  float* __restrict__ z, int N) {
    const int node = blockIdx.x * 4 + (threadIdx.x >> 6);
    if (node >= N) return;
    const int lane = threadIdx.x & 63;
    const size_t o = (size_t)node * CAP;
    const int dg = cnt[node];

    float4 acc = {0.f, 0.f, 0.f, 0.f};
    int e = 0;
    for (; e + 4 <= dg; e += 4) {
        const int2 p0 = pairs[o + e];
        const int2 p1 = pairs[o + e + 1];
        const int2 p2 = pairs[o + e + 2];
        const int2 p3 = pairs[o + e + 3];
        const uint2 h0 = *reinterpret_cast<const uint2*>(&h[(size_t)p0.x * D + lane * 4]);
        const uint2 h1 = *reinterpret_cast<const uint2*>(&h[(size_t)p1.x * D + lane * 4]);
        const uint2 h2 = *reinterpret_cast<const uint2*>(&h[(size_t)p2.x * D + lane * 4]);
        const uint2 h3 = *reinterpret_cast<const uint2*>(&h[(size_t)p3.x * D + lane * 4]);
        const float v0 = __int_as_float(p0.y);
        const float v1 = __int_as_float(p1.y);
        const float v2 = __int_as_float(p2.y);
        const float v3 = __int_as_float(p3.y);
        acc.x = fmaf(v0, __uint_as_float(h0.x << 16), acc.x);
        acc.y = fmaf(v0, __uint_as_float(h0.x & 0xffff0000u), acc.y);
        acc.z = fmaf(v0, __uint_as_float(h0.y << 16), acc.z);
        acc.w = fmaf(v0, __uint_as_float(h0.y & 0xffff0000u), acc.w);
        acc.x = fmaf(v1, __uint_as_float(h1.x << 16), acc.x);
        acc.y = fmaf(v1, __uint_as_float(h1.x & 0xffff0000u), acc.y);
        acc.z = fmaf(v1, __uint_as_float(h1.y << 16), acc.z);
        acc.w = fmaf(v1, __uint_as_float(h1.y & 0xffff0000u), acc.w);
        acc.x = fmaf(v2, __uint_as_float(h2.x << 16), acc.x);
        acc.y = fmaf(v2, __uint_as_float(h2.x & 0xffff0000u), acc.y);
        acc.z = fmaf(v2, __uint_as_float(h2.y << 16), acc.z);
        acc.w = fmaf(v2, __uint_as_float(h2.y & 0xffff0000u), acc.w);
        acc.x = fmaf(v3, __uint_as_float(h3.x << 16), acc.x);
        acc.y = fmaf(v3, __uint_as_float(h3.x & 0xffff0000u), acc.y);
        acc.z = fmaf(v3, __uint_as_float(h3.y << 16), acc.z);
        acc.w = fmaf(v3, __uint_as_float(h3.y & 0xffff0000u), acc.w);
    }
    for (; e < dg; ++e) {
        const int2 p0 = pairs[o + e];
        const float v0 = __int_as_float(p0.y);
        const uint2 h0 = *reinterpret_cast<const uint2*>(&h[(size_t)p0.x * D + lane * 4]);
        acc.x = fmaf(v0, __uint_as_float(h0.x << 16), acc.x);
        acc.y = fmaf(v0, __uint_as_float(h0.x & 0xffff0000u), acc.y);
        acc.z = fmaf(v0, __uint_as_float(h0.y << 16), acc.z);
        acc.w = fmaf(v0, __uint_as_float(h0.y & 0xffff0000u), acc.w);
    }

    const float4 bb = *reinterpret_cast<const float4*>(&b[lane * 4]);
    acc.x = fmaxf(acc.x + bb.x, 0.f);
    acc.y = fmaxf(acc.y + bb.y, 0.f);
    acc.z = fmaxf(acc.z + bb.z, 0.f);
    acc.w = fmaxf(acc.w + bb.w, 0.f);
    *reinterpret_cast<float4*>(&z[(size_t)node * D + lane * 4]) = acc;
}

extern "C" void kernel_launch(void* const* d_in, const int* in_sizes, int n_in,
                              void* d_out, int out_size, void* d_ws, size_t ws_size,
                              hipStream_t stream) {
    const int*   edge_src = (const int*)d_in[0];
    const int*   edge_dst = (const int*)d_in[1];
    const float* edge_val = (const float*)d_in[2];
    const float* x        = (const float*)d_in[3];
    const float* W        = (const float*)d_in[4];
    const float* b        = (const float*)d_in[5];

    const int E = in_sizes[0];
    const int N = in_sizes[3] / D;
    const int nch = (E + CHUNK - 1) / CHUNK;   // 196
    const int nb  = (N + 255) >> 8;            // 196 (<= 256)

    float* z = (float*)d_out;

    // workspace layout (~58 MB)
    unsigned short* h     = (unsigned short*)d_ws;                      // N*D bf16 (25.6 MB)
    int2*           pairs = (int2*)(h + (size_t)N * D);                 // N*CAP int2 (25.6 MB)
    int2*           eds   = pairs + (size_t)N * CAP;                    // E int2 (6.4 MB)
    unsigned short* Wt    = (unsigned short*)(eds + E);                 // 128 KB
    int* partial     = (int*)(Wt + D * D);                              // nb*nch
    int* bucketStart = partial + nb * nch;                              // nb+1
    int* cnt         = bucketStart + (nb + 1);                          // N (fully written by finalize)
    int* rowSum      = cnt + N;                                         // nb (must be zeroed)

    hipMemsetAsync(rowSum, 0, (size_t)nb * sizeof(int), stream);

    k_prep<<<256 + nch, 256, 0, stream>>>(W, Wt, edge_dst, partial, rowSum, E, nch, nb);

    const int nscan = (nb + 3) / 4;
    k_scan<<<nscan + 1, 256, 0, stream>>>(partial, rowSum, bucketStart, nch, nb, nscan);

    const int gm = (N + BMT - 1) / BMT;        // 782 m-blocks total
    const int gA = (gm * 3) / 5;               // ~60% alongside scatter
    const int gB = gm - gA;                    // rest alongside finalize

    k_mainA<<<nch + gA, 256, 0, stream>>>(edge_src, edge_dst, edge_val, partial,
                                          bucketStart, eds, E, nch, nb,
                                          x, Wt, h, N);

    k_mainB<<<nb + gB, 256, 0, stream>>>(eds, bucketStart, pairs, cnt, N, nb,
                                         x, Wt, h, N, gA);

    gather_csr<<<(N + 3) / 4, 256, 0, stream>>>(pairs, cnt, h, b, z, N);
}